// Round 9
// baseline (2492.300 us; speedup 1.0000x reference)
//
#include <hip/hip_runtime.h>
#include <math.h>

#define NB 32
#define NC 72
#define NT 1000
#define NF 64
#define NH 512
#define NCLS 3

// ---- workspace layout (float indices) ----
#define OFF_FEATS   0            // feats[b][t][f], 32*1000*64
#define OFF_POOLED  2048000      // pooled[b][h], 32*512
#define OFF_HX      2064384      // u64 hx[2][b][h] = {epoch:32|fp32:32} agent channel
#define OFF_HFA     2129920      // u64 hfa[2][b][h] same payload, local-L2 fast channel
#define WS_FLOATS   2195456

// pad every 32 h-elements by 4 slots: 16 p-chunks land 2-way on banks (free per m136)
#define HIDX2(k) ((k) + (((k) >> 5) << 2))
#define HPAD (NH + 64)

// ---------------- prep: epoch reset (MUST run every launch/replay) ----
__global__ void prep_kernel(unsigned long long* __restrict__ sync_area) {
  int i = blockIdx.x * 256 + threadIdx.x;   // hx + hfa contiguous: 65536 u64
  if (i < 65536) sync_area[i] = 0ull;       // stale epochs would satisfy exact polls
}

// ---------------- fused front-end: conv5 + BN1 + ELU + spatial + BN2 + ELU ----
__global__ __launch_bounds__(256) void frontend_kernel(
    const float* __restrict__ x, const float* __restrict__ w_temp,
    const float* __restrict__ g1, const float* __restrict__ be1,
    const float* __restrict__ m1, const float* __restrict__ v1,
    const float* __restrict__ wsp,
    const float* __restrict__ g2, const float* __restrict__ be2,
    const float* __restrict__ m2, const float* __restrict__ v2,
    float* __restrict__ feats) {
  const int b = blockIdx.y;
  const int t0 = blockIdx.x * 64;

  __shared__ float xs[NC][68];
  for (int idx = threadIdx.x; idx < NC * 68; idx += 256) {
    int c = idx / 68, tt = idx % 68;
    int tg = t0 - 2 + tt;
    xs[c][tt] = (tg >= 0 && tg < NT) ? x[(b * NC + c) * NT + tg] : 0.0f;
  }
  __syncthreads();

  const int f = threadIdx.x & 63;
  const int tq = threadIdx.x >> 6;

  const float w0 = w_temp[f * 5 + 0], w1 = w_temp[f * 5 + 1], w2 = w_temp[f * 5 + 2],
              w3 = w_temp[f * 5 + 3], w4 = w_temp[f * 5 + 4];
  const float sc1 = g1[f] * rsqrtf(v1[f] + 1e-5f);
  const float sh1 = be1[f] - m1[f] * sc1;
  const float sc2 = g2[f] * rsqrtf(v2[f] + 1e-5f);
  const float sh2 = be2[f] - m2[f] * sc2;

  for (int i = 0; i < 16; ++i) {
    const int tl = tq + 4 * i;
    const int t = t0 + tl;
    if (t >= NT) break;
    float acc = 0.0f;
    for (int c = 0; c < NC; ++c) {
      const float* xr = &xs[c][tl];
      float conv = xr[0] * w0 + xr[1] * w1 + xr[2] * w2 + xr[3] * w3 + xr[4] * w4;
      float bn = conv * sc1 + sh1;
      float e = bn > 0.0f ? bn : __expf(bn) - 1.0f;
      acc += e * wsp[f * NC + c];
    }
    float bn2 = acc * sc2 + sh2;
    float e2 = bn2 > 0.0f ? bn2 : __expf(bn2) - 1.0f;
    feats[(b * NT + t) * NF + f] = e2;
  }
}

// ---------------- ESN scan: 32 batches x 4 col-groups (r4 skeleton) ----
// Exchange: dual-publish u64 {epoch|fp32}. hfa read via WORKGROUP-scope 64-bit
// fetch_add(0): executes in the LOCAL XCD L2 (atomics bypass L1) -> fast when
// producer is co-XCD (r8's truncation failure proved this path delivers).
// hx agent-scope is the coherent fallback; identical payload -> bit-identical
// output regardless of channel. Epoch-exact match filters stale lines; add-0
// RMW preserves payloads; budget degrades to wrong-answer instead of hang.
__global__ __launch_bounds__(512, 1) void esn_scan(
    const float* __restrict__ Wm, const float* __restrict__ w_in,
    const float* __restrict__ b_in, const float* __restrict__ feats,
    unsigned long long* __restrict__ hx, unsigned long long* __restrict__ hfa,
    float* __restrict__ pooled) {
  const int b = blockIdx.x & 31;    // members {b,b+32,b+64,b+96} = b mod 8 -> same XCD
  const int m = blockIdx.x >> 5;    // col-group 0..3 (128 cols each)
  const int tid = threadIdx.x;      // 0..511
  const int grp = tid >> 4;         // 0..31
  const int p = tid & 15;           // k-chunk / f-chunk
  const int c0 = m * 128 + grp * 4; // base column of this thread's 4 cols

  __shared__ __align__(16) float h2[2][HPAD];
  __shared__ __align__(16) float f2[2][NF];

  // W slice: 4 cols x k in [p*32, p*32+32)  (r4-exact load + pin)
  float w[4][32];
#pragma unroll
  for (int c = 0; c < 4; ++c)
#pragma unroll
    for (int i = 0; i < 32; i += 4) {
      float4 t = *(const float4*)&Wm[(c0 + c) * NH + p * 32 + i];
      w[c][i] = t.x; w[c][i + 1] = t.y; w[c][i + 2] = t.z; w[c][i + 3] = t.w;
    }
#pragma unroll
  for (int c = 0; c < 4; ++c)
#pragma unroll
    for (int i = 0; i < 32; ++i) asm volatile("" : "+v"(w[c][i]));

  float wu[4][4];
#pragma unroll
  for (int c = 0; c < 4; ++c) {
    float4 t = *(const float4*)&w_in[(c0 + c) * NF + p * 4];
    wu[c][0] = t.x; wu[c][1] = t.y; wu[c][2] = t.z; wu[c][3] = t.w;
  }
  float be[4];
  {
    float4 bv = *(const float4*)&b_in[c0];
    be[0] = p == 0 ? bv.x : 0.0f; be[1] = p == 0 ? bv.y : 0.0f;
    be[2] = p == 0 ? bv.z : 0.0f; be[3] = p == 0 ? bv.w : 0.0f;
  }

  for (int i = tid; i < HPAD; i += 512) h2[0][i] = 0.0f;
  if (tid < NF) f2[0][tid] = feats[(b * NT) * NF + tid];
  __syncthreads();

  float* hc = &h2[0][0];
  float* hb = &h2[1][0];
  float* fc = &f2[0][0];
  float* fb = &f2[1][0];

  float pool = 0.0f;
  int budget = 300000;   // safety: degrade to wrong-answer instead of hang
  int fast_hits = 0;
  bool fast_ok = false;

#pragma unroll 1
  for (int t = 0; t < NT; ++t) {
    float acc[4] = {be[0], be[1], be[2], be[3]};
    {
      float4 fv = *(const float4*)&fc[p * 4];
#pragma unroll
      for (int c = 0; c < 4; ++c)
        acc[c] += fv.x * wu[c][0] + fv.y * wu[c][1] + fv.z * wu[c][2] + fv.w * wu[c][3];
    }
#pragma unroll
    for (int i = 0; i < 8; ++i) {       // h chunk contiguous: hc[p*36 .. p*36+32)
      float4 hv = *(const float4*)&hc[p * 36 + i * 4];
#pragma unroll
      for (int c = 0; c < 4; ++c)
        acc[c] += hv.x * w[c][i * 4] + hv.y * w[c][i * 4 + 1] +
                  hv.z * w[c][i * 4 + 2] + hv.w * w[c][i * 4 + 3];
    }
#pragma unroll
    for (int c = 0; c < 4; ++c) {       // 16-lane butterfly (DPP, no LDS)
      acc[c] += __shfl_xor(acc[c], 1);
      acc[c] += __shfl_xor(acc[c], 2);
      acc[c] += __shfl_xor(acc[c], 4);
      acc[c] += __shfl_xor(acc[c], 8);
    }

    const int par = (t + 1) & 1;
    unsigned long long* hxb = hx + par * (NB * NH) + b * NH;
    unsigned long long* hfab = hfa + par * (NB * NH) + b * NH;
    if (p < 4) {                        // thread p finalizes column c0+p
      const int j = c0 + p;
      float asel = p == 0 ? acc[0] : p == 1 ? acc[1] : p == 2 ? acc[2] : acc[3];
      float hn = 0.9f * hc[HIDX2(j)] + 0.1f * tanhf(asel);
      pool += hn;
      if (t < NT - 1) {
        unsigned long long pk =
            ((unsigned long long)(unsigned)(t + 1) << 32) | (unsigned)__float_as_uint(hn);
        __hip_atomic_store(&hfab[j], pk, __ATOMIC_RELAXED, __HIP_MEMORY_SCOPE_WORKGROUP);
        __hip_atomic_store(&hxb[j], pk, __ATOMIC_RELAXED, __HIP_MEMORY_SCOPE_AGENT);
        hb[HIDX2(j)] = hn;              // own column: no round trip
      }
    }
    if (t == NT - 1) break;

    // prefetch next feats row; latency hides under the poll
    float fnext = 0.0f;
    if (tid < NF) fnext = feats[(b * NT + t + 1) * NF + tid];

    const int k = tid;                  // 512 threads cover the 512 h-values
    if ((k >> 7) != m) {                // poll the other 3 groups' values
      const unsigned e = (unsigned)(t + 1);
      unsigned long long q = 0;
      if (t < 4) {
        // trial: probe both channels, full precision either way
        bool fhit = false;
        for (;;) {
          unsigned long long qf = __hip_atomic_fetch_add(
              &hfab[k], 0ull, __ATOMIC_RELAXED, __HIP_MEMORY_SCOPE_WORKGROUP);
          if ((unsigned)(qf >> 32) == e) { q = qf; fhit = true; break; }
          unsigned long long qs =
              __hip_atomic_load(&hxb[k], __ATOMIC_RELAXED, __HIP_MEMORY_SCOPE_AGENT);
          if ((unsigned)(qs >> 32) == e) { q = qs; break; }
          if (--budget < 0) break;
        }
        if (fhit) ++fast_hits;
        if (t == 3) fast_ok = (fast_hits >= 2);
      } else if (fast_ok) {
        // committed fast: local-L2 atomic probes, slow fallback every 8 for liveness
        bool hit = false;
        for (;;) {
          for (int r = 0; r < 8; ++r) {
            unsigned long long qf = __hip_atomic_fetch_add(
                &hfab[k], 0ull, __ATOMIC_RELAXED, __HIP_MEMORY_SCOPE_WORKGROUP);
            if ((unsigned)(qf >> 32) == e) { q = qf; hit = true; break; }
          }
          if (hit) break;
          unsigned long long qs =
              __hip_atomic_load(&hxb[k], __ATOMIC_RELAXED, __HIP_MEMORY_SCOPE_AGENT);
          if ((unsigned)(qs >> 32) == e) { q = qs; break; }
          if (--budget < 0) break;
        }
      } else {
        // committed slow: r4-exact agent-scope poll
        for (;;) {
          q = __hip_atomic_load(&hxb[k], __ATOMIC_RELAXED, __HIP_MEMORY_SCOPE_AGENT);
          if ((unsigned)(q >> 32) == e) break;
          if (--budget < 0) break;
          __builtin_amdgcn_s_sleep(1);
        }
      }
      hb[HIDX2(k)] = __uint_as_float((unsigned)q);
    }
    if (tid < NF) fb[tid] = fnext;
    __syncthreads();                    // ONE barrier per step
    { float* tp = hc; hc = hb; hb = tp; }
    { float* tp = fc; fc = fb; fb = tp; }
  }

  if (p < 4) pooled[b * NH + c0 + p] = pool * (1.0f / NT);
}

// ---------------- classifier head ----
__global__ void classifier_kernel(const float* __restrict__ pooled,
                                  const float* __restrict__ w_cls,
                                  const float* __restrict__ b_cls,
                                  float* __restrict__ out) {
  const int b = blockIdx.x;
  const int lane = threadIdx.x;  // 64
  float a0 = 0.0f, a1 = 0.0f, a2 = 0.0f;
  for (int jj = lane; jj < NH; jj += 64) {
    float pv = pooled[b * NH + jj];
    a0 += pv * w_cls[0 * NH + jj];
    a1 += pv * w_cls[1 * NH + jj];
    a2 += pv * w_cls[2 * NH + jj];
  }
  for (int off = 32; off; off >>= 1) {
    a0 += __shfl_down(a0, off);
    a1 += __shfl_down(a1, off);
    a2 += __shfl_down(a2, off);
  }
  if (lane == 0) {
    out[b * NCLS + 0] = a0 + b_cls[0];
    out[b * NCLS + 1] = a1 + b_cls[1];
    out[b * NCLS + 2] = a2 + b_cls[2];
  }
}

extern "C" void kernel_launch(void* const* d_in, const int* in_sizes, int n_in,
                              void* d_out, int out_size, void* d_ws, size_t ws_size,
                              hipStream_t stream) {
  (void)in_sizes; (void)n_in; (void)out_size;
  if (ws_size < (size_t)WS_FLOATS * 4) return;

  const float* x      = (const float*)d_in[0];
  const float* w_temp = (const float*)d_in[1];
  const float* g1  = (const float*)d_in[2];
  const float* be1 = (const float*)d_in[3];
  const float* m1  = (const float*)d_in[4];
  const float* v1  = (const float*)d_in[5];
  const float* wsp = (const float*)d_in[6];
  const float* g2  = (const float*)d_in[7];
  const float* be2 = (const float*)d_in[8];
  const float* m2  = (const float*)d_in[9];
  const float* v2  = (const float*)d_in[10];
  const float* w_in  = (const float*)d_in[11];
  const float* b_in  = (const float*)d_in[12];
  const float* Wm    = (const float*)d_in[13];
  const float* w_cls = (const float*)d_in[14];
  const float* b_cls = (const float*)d_in[15];

  float* ws_f  = (float*)d_ws;
  float* feats = ws_f + OFF_FEATS;
  float* pooledp = ws_f + OFF_POOLED;
  unsigned long long* hx = (unsigned long long*)(ws_f + OFF_HX);
  unsigned long long* hfa = (unsigned long long*)(ws_f + OFF_HFA);

  prep_kernel<<<256, 256, 0, stream>>>(hx);   // zeroes hx AND hfa (contiguous)

  dim3 gfe(16, NB);
  frontend_kernel<<<gfe, 256, 0, stream>>>(x, w_temp, g1, be1, m1, v1, wsp,
                                           g2, be2, m2, v2, feats);

  esn_scan<<<128, 512, 0, stream>>>(Wm, w_in, b_in, feats, hx, hfa, pooledp);

  classifier_kernel<<<NB, 64, 0, stream>>>(pooledp, w_cls, b_cls, (float*)d_out);
}

// Round 10
// 2211.965 us; speedup vs baseline: 1.1267x; 1.1267x over previous
//
#include <hip/hip_runtime.h>
#include <math.h>

#define NB 32
#define NC 72
#define NT 1000
#define NF 64
#define NH 512
#define NCLS 3

// ---- workspace layout (float indices) ----
#define OFF_FEATS   0            // feats[b][t][f], 32*1000*64
#define OFF_POOLED  2048000      // pooled[b][h], 32*512
#define OFF_HX      2064384      // u64 hx[2][b][h] = {epoch:32|fp32:32}
#define WS_FLOATS   2129920

// pad every 32 h-elements by 4 slots: 16 p-chunks land 2-way on banks (free per m136)
#define HIDX2(k) ((k) + (((k) >> 5) << 2))
#define HPAD (NH + 64)

// ---------------- prep: epoch reset (MUST run every launch/replay) ----
__global__ void prep_kernel(unsigned long long* __restrict__ hx) {
  int i = blockIdx.x * 256 + threadIdx.x;
  if (i < 2 * NB * NH) hx[i] = 0ull;   // stale epochs would satisfy exact-match polls
}

// ---------------- fused front-end: conv5 + BN1 + ELU + spatial + BN2 + ELU ----
__global__ __launch_bounds__(256) void frontend_kernel(
    const float* __restrict__ x, const float* __restrict__ w_temp,
    const float* __restrict__ g1, const float* __restrict__ be1,
    const float* __restrict__ m1, const float* __restrict__ v1,
    const float* __restrict__ wsp,
    const float* __restrict__ g2, const float* __restrict__ be2,
    const float* __restrict__ m2, const float* __restrict__ v2,
    float* __restrict__ feats) {
  const int b = blockIdx.y;
  const int t0 = blockIdx.x * 64;

  __shared__ float xs[NC][68];
  for (int idx = threadIdx.x; idx < NC * 68; idx += 256) {
    int c = idx / 68, tt = idx % 68;
    int tg = t0 - 2 + tt;
    xs[c][tt] = (tg >= 0 && tg < NT) ? x[(b * NC + c) * NT + tg] : 0.0f;
  }
  __syncthreads();

  const int f = threadIdx.x & 63;
  const int tq = threadIdx.x >> 6;

  const float w0 = w_temp[f * 5 + 0], w1 = w_temp[f * 5 + 1], w2 = w_temp[f * 5 + 2],
              w3 = w_temp[f * 5 + 3], w4 = w_temp[f * 5 + 4];
  const float sc1 = g1[f] * rsqrtf(v1[f] + 1e-5f);
  const float sh1 = be1[f] - m1[f] * sc1;
  const float sc2 = g2[f] * rsqrtf(v2[f] + 1e-5f);
  const float sh2 = be2[f] - m2[f] * sc2;

  for (int i = 0; i < 16; ++i) {
    const int tl = tq + 4 * i;
    const int t = t0 + tl;
    if (t >= NT) break;
    float acc = 0.0f;
    for (int c = 0; c < NC; ++c) {
      const float* xr = &xs[c][tl];
      float conv = xr[0] * w0 + xr[1] * w1 + xr[2] * w2 + xr[3] * w3 + xr[4] * w4;
      float bn = conv * sc1 + sh1;
      float e = bn > 0.0f ? bn : __expf(bn) - 1.0f;
      acc += e * wsp[f * NC + c];
    }
    float bn2 = acc * sc2 + sh2;
    float e2 = bn2 > 0.0f ? bn2 : __expf(bn2) - 1.0f;
    feats[(b * NT + t) * NF + f] = e2;
  }
}

// ---------------- ESN scan: r4 skeleton + staggered 5-probe poll ring ----
// Poll: 5 loads to the SAME address issued ~160ns apart (s_sleep(6)), checked
// oldest-first with counted vmcnt(4..0). Sampling cadence ~160ns instead of the
// serial ~900ns RTT. Un-hit probes are NOT drained: the step barrier is a raw
// lgkmcnt(0)+s_barrier (no implicit vmcnt(0)); pending probes retire under the
// next step's compiler-inserted wait at fb=fnext (free). Ring regs live across
// the loop (function scope + end sink). Epoch-exact match keeps any ordering
// correct; budget degrades to wrong-answer instead of hang.
__global__ __launch_bounds__(512, 1) void esn_scan(
    const float* __restrict__ Wm, const float* __restrict__ w_in,
    const float* __restrict__ b_in, const float* __restrict__ feats,
    unsigned long long* __restrict__ hx, float* __restrict__ pooled) {
  const int b = blockIdx.x & 31;    // members {b,b+32,b+64,b+96}: bid%8 const (XCD heuristic)
  const int m = blockIdx.x >> 5;    // col-group 0..3 (128 cols each)
  const int tid = threadIdx.x;      // 0..511
  const int grp = tid >> 4;         // 0..31
  const int p = tid & 15;           // k-chunk / f-chunk
  const int c0 = m * 128 + grp * 4; // base column of this thread's 4 cols

  __shared__ __align__(16) float h2[2][HPAD];
  __shared__ __align__(16) float f2[2][NF];

  // W slice: 4 cols x k in [p*32, p*32+32)  (r4-exact load + pin)
  float w[4][32];
#pragma unroll
  for (int c = 0; c < 4; ++c)
#pragma unroll
    for (int i = 0; i < 32; i += 4) {
      float4 t = *(const float4*)&Wm[(c0 + c) * NH + p * 32 + i];
      w[c][i] = t.x; w[c][i + 1] = t.y; w[c][i + 2] = t.z; w[c][i + 3] = t.w;
    }
#pragma unroll
  for (int c = 0; c < 4; ++c)
#pragma unroll
    for (int i = 0; i < 32; ++i) asm volatile("" : "+v"(w[c][i]));

  float wu[4][4];
#pragma unroll
  for (int c = 0; c < 4; ++c) {
    float4 t = *(const float4*)&w_in[(c0 + c) * NF + p * 4];
    wu[c][0] = t.x; wu[c][1] = t.y; wu[c][2] = t.z; wu[c][3] = t.w;
  }
  float be[4];
  {
    float4 bv = *(const float4*)&b_in[c0];
    be[0] = p == 0 ? bv.x : 0.0f; be[1] = p == 0 ? bv.y : 0.0f;
    be[2] = p == 0 ? bv.z : 0.0f; be[3] = p == 0 ? bv.w : 0.0f;
  }

  for (int i = tid; i < HPAD; i += 512) h2[0][i] = 0.0f;
  if (tid < NF) f2[0][tid] = feats[(b * NT) * NF + tid];
  __syncthreads();

  float* hc = &h2[0][0];
  float* hb = &h2[1][0];
  float* fc = &f2[0][0];
  float* fb = &f2[1][0];

  float pool = 0.0f;
  int budget = 200000;   // burst budget: worst-case bail ~0.3s, no hang
  unsigned long long a0 = 0, a1 = 0, a2 = 0, a3 = 0, a4 = 0;  // probe ring (live whole loop)

#pragma unroll 1
  for (int t = 0; t < NT; ++t) {
    // issue next feats row FIRST: returns during the matvec; its compiler wait
    // at fb=fnext also retires last step's pending ring probes for free
    float fnext = 0.0f;
    if (tid < NF && t < NT - 1) fnext = feats[(b * NT + t + 1) * NF + tid];

    float acc[4] = {be[0], be[1], be[2], be[3]};
    {
      float4 fv = *(const float4*)&fc[p * 4];
#pragma unroll
      for (int c = 0; c < 4; ++c)
        acc[c] += fv.x * wu[c][0] + fv.y * wu[c][1] + fv.z * wu[c][2] + fv.w * wu[c][3];
    }
#pragma unroll
    for (int i = 0; i < 8; ++i) {       // h chunk contiguous: hc[p*36 .. p*36+32)
      float4 hv = *(const float4*)&hc[p * 36 + i * 4];
#pragma unroll
      for (int c = 0; c < 4; ++c)
        acc[c] += hv.x * w[c][i * 4] + hv.y * w[c][i * 4 + 1] +
                  hv.z * w[c][i * 4 + 2] + hv.w * w[c][i * 4 + 3];
    }
#pragma unroll
    for (int c = 0; c < 4; ++c) {       // 16-lane butterfly (DPP, no LDS)
      acc[c] += __shfl_xor(acc[c], 1);
      acc[c] += __shfl_xor(acc[c], 2);
      acc[c] += __shfl_xor(acc[c], 4);
      acc[c] += __shfl_xor(acc[c], 8);
    }

    const int par = (t + 1) & 1;
    unsigned long long* hxb = hx + par * (NB * NH) + b * NH;
    if (p < 4) {                        // thread p finalizes column c0+p
      const int j = c0 + p;
      float asel = p == 0 ? acc[0] : p == 1 ? acc[1] : p == 2 ? acc[2] : acc[3];
      float hn = 0.9f * hc[HIDX2(j)] + 0.1f * tanhf(asel);
      pool += hn;
      if (t < NT - 1) {
        unsigned long long pk =
            ((unsigned long long)(unsigned)(t + 1) << 32) | (unsigned)__float_as_uint(hn);
        __hip_atomic_store(&hxb[j], pk, __ATOMIC_RELAXED, __HIP_MEMORY_SCOPE_AGENT);
        hb[HIDX2(j)] = hn;              // own column: no round trip
      }
    }
    if (t == NT - 1) break;

    if (tid < NF) fb[tid] = fnext;      // compiler wait here drains old probes

    const int k = tid;                  // 512 threads cover the 512 h-values
    if ((k >> 7) != m) {                // poll the other 3 groups' values
      const unsigned e = (unsigned)(t + 1);
      const unsigned long long* ap = &hxb[k];
      unsigned long long qv = 0;
      bool got = false;
      while (!got && --budget >= 0) {
        // burst: 5 staggered probes, samples ~450/610/770/930/1090ns after start
        asm volatile("global_load_dwordx2 %0, %1, off sc1" : "=v"(a0) : "v"(ap));
        __builtin_amdgcn_s_sleep(6);
        asm volatile("global_load_dwordx2 %0, %1, off sc1" : "=v"(a1) : "v"(ap));
        __builtin_amdgcn_s_sleep(6);
        asm volatile("global_load_dwordx2 %0, %1, off sc1" : "=v"(a2) : "v"(ap));
        __builtin_amdgcn_s_sleep(6);
        asm volatile("global_load_dwordx2 %0, %1, off sc1" : "=v"(a3) : "v"(ap));
        __builtin_amdgcn_s_sleep(6);
        asm volatile("global_load_dwordx2 %0, %1, off sc1" : "=v"(a4) : "v"(ap));
        asm volatile("s_waitcnt vmcnt(4)" ::: "memory");
        __builtin_amdgcn_sched_barrier(0);
        if ((unsigned)(a0 >> 32) == e) { qv = a0; got = true; }
        if (!got) {
          asm volatile("s_waitcnt vmcnt(3)" ::: "memory");
          __builtin_amdgcn_sched_barrier(0);
          if ((unsigned)(a1 >> 32) == e) { qv = a1; got = true; }
        }
        if (!got) {
          asm volatile("s_waitcnt vmcnt(2)" ::: "memory");
          __builtin_amdgcn_sched_barrier(0);
          if ((unsigned)(a2 >> 32) == e) { qv = a2; got = true; }
        }
        if (!got) {
          asm volatile("s_waitcnt vmcnt(1)" ::: "memory");
          __builtin_amdgcn_sched_barrier(0);
          if ((unsigned)(a3 >> 32) == e) { qv = a3; got = true; }
        }
        if (!got) {
          asm volatile("s_waitcnt vmcnt(0)" ::: "memory");
          __builtin_amdgcn_sched_barrier(0);
          if ((unsigned)(a4 >> 32) == e) { qv = a4; got = true; }
        }
      }
      hb[HIDX2(k)] = __uint_as_float((unsigned)qv);
    }

    // raw barrier: LDS drained (lgkmcnt), pending ring probes ride across
    asm volatile("s_waitcnt lgkmcnt(0)" ::: "memory");
    __builtin_amdgcn_sched_barrier(0);
    __builtin_amdgcn_s_barrier();
    __builtin_amdgcn_sched_barrier(0);

    { float* tp = hc; hc = hb; hb = tp; }
    { float* tp = fc; fc = fb; fb = tp; }
  }

  // retire any still-pending probes before regs can be reused; keep ring live
  asm volatile("s_waitcnt vmcnt(0)" ::: "memory");
  asm volatile("" :: "v"(a0), "v"(a1), "v"(a2), "v"(a3), "v"(a4));

  if (p < 4) pooled[b * NH + c0 + p] = pool * (1.0f / NT);
}

// ---------------- classifier head ----
__global__ void classifier_kernel(const float* __restrict__ pooled,
                                  const float* __restrict__ w_cls,
                                  const float* __restrict__ b_cls,
                                  float* __restrict__ out) {
  const int b = blockIdx.x;
  const int lane = threadIdx.x;  // 64
  float a0 = 0.0f, a1 = 0.0f, a2 = 0.0f;
  for (int jj = lane; jj < NH; jj += 64) {
    float pv = pooled[b * NH + jj];
    a0 += pv * w_cls[0 * NH + jj];
    a1 += pv * w_cls[1 * NH + jj];
    a2 += pv * w_cls[2 * NH + jj];
  }
  for (int off = 32; off; off >>= 1) {
    a0 += __shfl_down(a0, off);
    a1 += __shfl_down(a1, off);
    a2 += __shfl_down(a2, off);
  }
  if (lane == 0) {
    out[b * NCLS + 0] = a0 + b_cls[0];
    out[b * NCLS + 1] = a1 + b_cls[1];
    out[b * NCLS + 2] = a2 + b_cls[2];
  }
}

extern "C" void kernel_launch(void* const* d_in, const int* in_sizes, int n_in,
                              void* d_out, int out_size, void* d_ws, size_t ws_size,
                              hipStream_t stream) {
  (void)in_sizes; (void)n_in; (void)out_size;
  if (ws_size < (size_t)WS_FLOATS * 4) return;

  const float* x      = (const float*)d_in[0];
  const float* w_temp = (const float*)d_in[1];
  const float* g1  = (const float*)d_in[2];
  const float* be1 = (const float*)d_in[3];
  const float* m1  = (const float*)d_in[4];
  const float* v1  = (const float*)d_in[5];
  const float* wsp = (const float*)d_in[6];
  const float* g2  = (const float*)d_in[7];
  const float* be2 = (const float*)d_in[8];
  const float* m2  = (const float*)d_in[9];
  const float* v2  = (const float*)d_in[10];
  const float* w_in  = (const float*)d_in[11];
  const float* b_in  = (const float*)d_in[12];
  const float* Wm    = (const float*)d_in[13];
  const float* w_cls = (const float*)d_in[14];
  const float* b_cls = (const float*)d_in[15];

  float* ws_f  = (float*)d_ws;
  float* feats = ws_f + OFF_FEATS;
  float* pooledp = ws_f + OFF_POOLED;
  unsigned long long* hx = (unsigned long long*)(ws_f + OFF_HX);

  prep_kernel<<<128, 256, 0, stream>>>(hx);

  dim3 gfe(16, NB);
  frontend_kernel<<<gfe, 256, 0, stream>>>(x, w_temp, g1, be1, m1, v1, wsp,
                                           g2, be2, m2, v2, feats);

  esn_scan<<<128, 512, 0, stream>>>(Wm, w_in, b_in, feats, hx, pooledp);

  classifier_kernel<<<NB, 64, 0, stream>>>(pooledp, w_cls, b_cls, (float*)d_out);
}

// Round 11
// 1682.801 us; speedup vs baseline: 1.4810x; 1.3145x over previous
//
#include <hip/hip_runtime.h>
#include <math.h>

#define NB 32
#define NC 72
#define NT 1000
#define NF 64
#define NH 512
#define NCLS 3

// ---- workspace layout (float indices) ----
#define OFF_FEATS   0            // feats[b][t][f], 32*1000*64
#define OFF_POOLED  2048000      // pooled[b][h], 32*512
#define OFF_HX      2064384      // u64 hx[2][b][h] = {epoch:32|float:32} (8B aligned)
#define WS_FLOATS   2129920

// pad every 32 h-elements by 4 slots: 16 p-chunks land 2-way on banks (free per m136)
#define HIDX2(k) ((k) + (((k) >> 5) << 2))
#define HPAD (NH + 64)

// ---------------- prep: epoch reset (MUST run every launch/replay) ----
__global__ void prep_kernel(unsigned long long* __restrict__ hx) {
  int i = blockIdx.x * 256 + threadIdx.x;
  if (i < 2 * NB * NH) hx[i] = 0ull;   // stale epochs from a previous replay would
                                       // satisfy exact-match polls with old data
}

// ---------------- fused front-end: conv5 + BN1 + ELU + spatial + BN2 + ELU ----
__global__ __launch_bounds__(256) void frontend_kernel(
    const float* __restrict__ x, const float* __restrict__ w_temp,
    const float* __restrict__ g1, const float* __restrict__ be1,
    const float* __restrict__ m1, const float* __restrict__ v1,
    const float* __restrict__ wsp,
    const float* __restrict__ g2, const float* __restrict__ be2,
    const float* __restrict__ m2, const float* __restrict__ v2,
    float* __restrict__ feats) {
  const int b = blockIdx.y;
  const int t0 = blockIdx.x * 64;

  __shared__ float xs[NC][68];
  for (int idx = threadIdx.x; idx < NC * 68; idx += 256) {
    int c = idx / 68, tt = idx % 68;
    int tg = t0 - 2 + tt;
    xs[c][tt] = (tg >= 0 && tg < NT) ? x[(b * NC + c) * NT + tg] : 0.0f;
  }
  __syncthreads();

  const int f = threadIdx.x & 63;
  const int tq = threadIdx.x >> 6;

  const float w0 = w_temp[f * 5 + 0], w1 = w_temp[f * 5 + 1], w2 = w_temp[f * 5 + 2],
              w3 = w_temp[f * 5 + 3], w4 = w_temp[f * 5 + 4];
  const float sc1 = g1[f] * rsqrtf(v1[f] + 1e-5f);
  const float sh1 = be1[f] - m1[f] * sc1;
  const float sc2 = g2[f] * rsqrtf(v2[f] + 1e-5f);
  const float sh2 = be2[f] - m2[f] * sc2;

  for (int i = 0; i < 16; ++i) {
    const int tl = tq + 4 * i;
    const int t = t0 + tl;
    if (t >= NT) break;
    float acc = 0.0f;
    for (int c = 0; c < NC; ++c) {
      const float* xr = &xs[c][tl];
      float conv = xr[0] * w0 + xr[1] * w1 + xr[2] * w2 + xr[3] * w3 + xr[4] * w4;
      float bn = conv * sc1 + sh1;
      float e = bn > 0.0f ? bn : __expf(bn) - 1.0f;
      acc += e * wsp[f * NC + c];
    }
    float bn2 = acc * sc2 + sh2;
    float e2 = bn2 > 0.0f ? bn2 : __expf(bn2) - 1.0f;
    feats[(b * NT + t) * NF + f] = e2;
  }
}

// ---------------- ESN scan: 32 batches x 4 col-groups (r4 optimum, restored) ----
// Structural constraints measured r1-r10: W (1MB) cannot fit <4 CUs' register
// files (pool 512 regs/SIMD) -> 4-WG sync domain is forced; cross-CU exchange
// RTT ~1.1us via coherent point; plain agent-scope poll beat every alternative
// (sc0 channels, L2 atomics, probe rings, multi-batch). Do not re-litigate.
__global__ __launch_bounds__(512, 1) void esn_scan(
    const float* __restrict__ Wm, const float* __restrict__ w_in,
    const float* __restrict__ b_in, const float* __restrict__ feats,
    unsigned long long* __restrict__ hx, float* __restrict__ pooled) {
  const int b = blockIdx.x & 31;    // batch members share bid%8 -> same XCD heuristic
  const int m = blockIdx.x >> 5;    // col-group 0..3 (128 cols each)
  const int tid = threadIdx.x;      // 0..511
  const int grp = tid >> 4;         // 0..31
  const int p = tid & 15;           // k-chunk / f-chunk
  const int c0 = m * 128 + grp * 4; // base column of this thread's 4 cols

  __shared__ __align__(16) float h2[2][HPAD];
  __shared__ __align__(16) float f2[2][NF];

  // W slice: 4 cols x k in [p*32, p*32+32), per-thread-contiguous float4s
  float w[4][32];
#pragma unroll
  for (int c = 0; c < 4; ++c)
#pragma unroll
    for (int i = 0; i < 32; i += 4) {
      float4 t = *(const float4*)&Wm[(c0 + c) * NH + p * 32 + i];
      w[c][i] = t.x; w[c][i + 1] = t.y; w[c][i + 2] = t.z; w[c][i + 3] = t.w;
    }
#pragma unroll
  for (int c = 0; c < 4; ++c)
#pragma unroll
    for (int i = 0; i < 32; ++i) asm volatile("" : "+v"(w[c][i]));  // no remat into loop

  float wu[4][4];
#pragma unroll
  for (int c = 0; c < 4; ++c) {
    float4 t = *(const float4*)&w_in[(c0 + c) * NF + p * 4];
    wu[c][0] = t.x; wu[c][1] = t.y; wu[c][2] = t.z; wu[c][3] = t.w;
  }
  float be[4];
  {
    float4 bv = *(const float4*)&b_in[c0];
    be[0] = p == 0 ? bv.x : 0.0f; be[1] = p == 0 ? bv.y : 0.0f;
    be[2] = p == 0 ? bv.z : 0.0f; be[3] = p == 0 ? bv.w : 0.0f;
  }

  for (int i = tid; i < HPAD; i += 512) h2[0][i] = 0.0f;
  if (tid < NF) f2[0][tid] = feats[(b * NT) * NF + tid];
  __syncthreads();

  float* hc = &h2[0][0];
  float* hb = &h2[1][0];
  float* fc = &f2[0][0];
  float* fb = &f2[1][0];

  float pool = 0.0f;
  int budget = 20000000;  // safety: degrade to wrong-answer instead of hang

#pragma unroll 1
  for (int t = 0; t < NT; ++t) {
    float acc[4] = {be[0], be[1], be[2], be[3]};
    {
      float4 fv = *(const float4*)&fc[p * 4];
#pragma unroll
      for (int c = 0; c < 4; ++c)
        acc[c] += fv.x * wu[c][0] + fv.y * wu[c][1] + fv.z * wu[c][2] + fv.w * wu[c][3];
    }
#pragma unroll
    for (int i = 0; i < 8; ++i) {       // h chunk contiguous: hc[p*36 .. p*36+32)
      float4 hv = *(const float4*)&hc[p * 36 + i * 4];
#pragma unroll
      for (int c = 0; c < 4; ++c)
        acc[c] += hv.x * w[c][i * 4] + hv.y * w[c][i * 4 + 1] +
                  hv.z * w[c][i * 4 + 2] + hv.w * w[c][i * 4 + 3];
    }
#pragma unroll
    for (int c = 0; c < 4; ++c) {       // 16-lane butterfly (DPP, no LDS)
      acc[c] += __shfl_xor(acc[c], 1);
      acc[c] += __shfl_xor(acc[c], 2);
      acc[c] += __shfl_xor(acc[c], 4);
      acc[c] += __shfl_xor(acc[c], 8);
    }

    unsigned long long* hxb = hx + ((t + 1) & 1) * (NB * NH) + b * NH;
    if (p < 4) {                        // thread p finalizes column c0+p
      const int j = c0 + p;
      float asel = p == 0 ? acc[0] : p == 1 ? acc[1] : p == 2 ? acc[2] : acc[3];
      // fast tanh: 1 - 2/(e^{2x}+1); exact limits at +/-inf, fp32 err ~1e-6
      float ex = __expf(2.0f * asel);
      float th = 1.0f - 2.0f / (ex + 1.0f);
      float hn = 0.9f * hc[HIDX2(j)] + 0.1f * th;
      pool += hn;
      if (t < NT - 1) {
        unsigned long long pk =
            ((unsigned long long)(unsigned)(t + 1) << 32) | (unsigned)__float_as_uint(hn);
        __hip_atomic_store(&hxb[j], pk, __ATOMIC_RELAXED, __HIP_MEMORY_SCOPE_AGENT);
        hb[HIDX2(j)] = hn;              // own column: no round trip
      }
    }
    if (t == NT - 1) break;

    // prefetch next feats row; latency hides under the poll
    float fnext = 0.0f;
    if (tid < NF) fnext = feats[(b * NT + t + 1) * NF + tid];

    const int k = tid;                  // 512 threads cover the 512 h-values
    if ((k >> 7) != m) {                // poll the other 3 groups' values
      unsigned long long q;
      for (;;) {
        q = __hip_atomic_load(&hxb[k], __ATOMIC_RELAXED, __HIP_MEMORY_SCOPE_AGENT);
        if ((unsigned)(q >> 32) == (unsigned)(t + 1)) break;
        if (--budget < 0) break;
        __builtin_amdgcn_s_sleep(1);
      }
      hb[HIDX2(k)] = __uint_as_float((unsigned)q);
    }
    if (tid < NF) fb[tid] = fnext;
    __syncthreads();                    // ONE barrier per step
    { float* tp = hc; hc = hb; hb = tp; }
    { float* tp = fc; fc = fb; fb = tp; }
  }

  if (p < 4) pooled[b * NH + c0 + p] = pool * (1.0f / NT);
}

// ---------------- classifier head ----
__global__ void classifier_kernel(const float* __restrict__ pooled,
                                  const float* __restrict__ w_cls,
                                  const float* __restrict__ b_cls,
                                  float* __restrict__ out) {
  const int b = blockIdx.x;
  const int lane = threadIdx.x;  // 64
  float a0 = 0.0f, a1 = 0.0f, a2 = 0.0f;
  for (int jj = lane; jj < NH; jj += 64) {
    float pv = pooled[b * NH + jj];
    a0 += pv * w_cls[0 * NH + jj];
    a1 += pv * w_cls[1 * NH + jj];
    a2 += pv * w_cls[2 * NH + jj];
  }
  for (int off = 32; off; off >>= 1) {
    a0 += __shfl_down(a0, off);
    a1 += __shfl_down(a1, off);
    a2 += __shfl_down(a2, off);
  }
  if (lane == 0) {
    out[b * NCLS + 0] = a0 + b_cls[0];
    out[b * NCLS + 1] = a1 + b_cls[1];
    out[b * NCLS + 2] = a2 + b_cls[2];
  }
}

extern "C" void kernel_launch(void* const* d_in, const int* in_sizes, int n_in,
                              void* d_out, int out_size, void* d_ws, size_t ws_size,
                              hipStream_t stream) {
  (void)in_sizes; (void)n_in; (void)out_size;
  if (ws_size < (size_t)WS_FLOATS * 4) return;

  const float* x      = (const float*)d_in[0];
  const float* w_temp = (const float*)d_in[1];
  const float* g1  = (const float*)d_in[2];
  const float* be1 = (const float*)d_in[3];
  const float* m1  = (const float*)d_in[4];
  const float* v1  = (const float*)d_in[5];
  const float* wsp = (const float*)d_in[6];
  const float* g2  = (const float*)d_in[7];
  const float* be2 = (const float*)d_in[8];
  const float* m2  = (const float*)d_in[9];
  const float* v2  = (const float*)d_in[10];
  const float* w_in  = (const float*)d_in[11];
  const float* b_in  = (const float*)d_in[12];
  const float* Wm    = (const float*)d_in[13];
  const float* w_cls = (const float*)d_in[14];
  const float* b_cls = (const float*)d_in[15];

  float* ws_f  = (float*)d_ws;
  float* feats = ws_f + OFF_FEATS;
  float* pooledp = ws_f + OFF_POOLED;
  unsigned long long* hx = (unsigned long long*)(ws_f + OFF_HX);

  prep_kernel<<<128, 256, 0, stream>>>(hx);

  dim3 gfe(16, NB);
  frontend_kernel<<<gfe, 256, 0, stream>>>(x, w_temp, g1, be1, m1, v1, wsp,
                                           g2, be2, m2, v2, feats);

  esn_scan<<<128, 512, 0, stream>>>(Wm, w_in, b_in, feats, hx, pooledp);

  classifier_kernel<<<NB, 64, 0, stream>>>(pooledp, w_cls, b_cls, (float*)d_out);
}